// Round 1
// baseline (270.761 us; speedup 1.0000x reference)
//
#include <hip/hip_runtime.h>
#include <math.h>

#define N_NODES 4096
#define E_EDGES 131072
#define EL_TOTAL (E_EDGES + N_NODES)
#define NEG_SLOPE 0.2f

// ---------- helpers ----------

// order-preserving float<->uint encoding (for atomicMax on floats of any sign)
__device__ __forceinline__ unsigned enc_f(float f) {
    unsigned u = __float_as_uint(f);
    return (u & 0x80000000u) ? ~u : (u | 0x80000000u);
}
__device__ __forceinline__ float dec_f(unsigned u) {
    return (u & 0x80000000u) ? __uint_as_float(u ^ 0x80000000u)
                             : __uint_as_float(~u);
}
__device__ __forceinline__ float lrelu(float x) {
    return x >= 0.0f ? x : NEG_SLOPE * x;
}
// edge j of the self-loop-augmented list: j<E -> edge_index, else self loop
__device__ __forceinline__ void edge_sd(const int* __restrict__ ei, int j, int& s, int& d) {
    if (j < E_EDGES) { s = ei[j]; d = ei[E_EDGES + j]; }
    else             { s = j - E_EDGES; d = s; }
}

// ---------- per-layer kernels ----------

// computes z = h @ W^T, zs = z@a_s, zd = z@a_d; inits m_enc/ssum/acc.
// If PREV_BIAS_RELU, input h = relu(hin + bprev) (folds previous layer's epilogue).
template<int F_IN, int F_OUT, bool PREV_BIAS_RELU>
__global__ void k_node_prep(const float* __restrict__ hin, const float* __restrict__ bprev,
                            const float* __restrict__ W, const float* __restrict__ a_s,
                            const float* __restrict__ a_d,
                            float* __restrict__ z, float* __restrict__ zs, float* __restrict__ zd,
                            unsigned* __restrict__ m_enc, float* __restrict__ ssum,
                            float* __restrict__ acc) {
    int i = blockIdx.x * blockDim.x + threadIdx.x;
    if (i >= N_NODES) return;
    float h[F_IN];
#pragma unroll
    for (int m = 0; m < F_IN; ++m) {
        float v = hin[i * F_IN + m];
        if constexpr (PREV_BIAS_RELU) { v = v + bprev[m]; v = v > 0.0f ? v : 0.0f; }
        h[m] = v;
    }
    float zsv = 0.0f, zdv = 0.0f;
#pragma unroll
    for (int k = 0; k < F_OUT; ++k) {
        float zv = 0.0f;
#pragma unroll
        for (int m = 0; m < F_IN; ++m) zv += h[m] * W[k * F_IN + m];
        z[i * F_OUT + k] = zv;
        zsv += zv * a_s[k];
        zdv += zv * a_d[k];
        acc[i * F_OUT + k] = 0.0f;
    }
    zs[i] = zsv;
    zd[i] = zdv;
    m_enc[i] = 0u;      // < encoding of any finite float
    ssum[i] = 0.0f;
}

__global__ void k_edge_max(const int* __restrict__ ei, const float* __restrict__ zs,
                           const float* __restrict__ zd, unsigned* __restrict__ m_enc) {
    int j = blockIdx.x * blockDim.x + threadIdx.x;
    if (j >= EL_TOTAL) return;
    int s, d; edge_sd(ei, j, s, d);
    float e = lrelu(zs[s] + zd[d]);
    atomicMax(&m_enc[d], enc_f(e));
}

__global__ void k_edge_sum(const int* __restrict__ ei, const float* __restrict__ zs,
                           const float* __restrict__ zd, const unsigned* __restrict__ m_enc,
                           float* __restrict__ ssum) {
    int j = blockIdx.x * blockDim.x + threadIdx.x;
    if (j >= EL_TOTAL) return;
    int s, d; edge_sd(ei, j, s, d);
    float e = lrelu(zs[s] + zd[d]);
    unsigned mu = m_enc[d];
    float m = (mu == 0u) ? 0.0f : dec_f(mu);   // replicates where(isfinite(m), m, 0)
    atomicAdd(&ssum[d], expf(e - m));
}

template<int F_OUT>
__global__ void k_edge_acc(const int* __restrict__ ei, const float* __restrict__ zs,
                           const float* __restrict__ zd, const unsigned* __restrict__ m_enc,
                           const float* __restrict__ ssum, const float* __restrict__ z,
                           float* __restrict__ acc) {
    int j = blockIdx.x * blockDim.x + threadIdx.x;
    if (j >= EL_TOTAL) return;
    int s, d; edge_sd(ei, j, s, d);
    float e = lrelu(zs[s] + zd[d]);
    unsigned mu = m_enc[d];
    float m = (mu == 0u) ? 0.0f : dec_f(mu);
    float wgt = expf(e - m);
    float a = wgt / (ssum[d] + 1e-16f);
#pragma unroll
    for (int k = 0; k < F_OUT; ++k)
        atomicAdd(&acc[d * F_OUT + k], a * z[s * F_OUT + k]);
}

// ---------- softmax + chain prep (single block) ----------

__global__ __launch_bounds__(1024) void k_softmax_prep(
        const float* __restrict__ acc3, const float* __restrict__ b3,
        const float* __restrict__ phi1, const float* __restrict__ phi2,
        float* __restrict__ xo, float* __restrict__ xf,
        float* __restrict__ scal, unsigned long long* __restrict__ nextkey) {
    __shared__ float red[1024];
    __shared__ int   redi[1024];
    int t = threadIdx.x;

    for (int i = t; i < N_NODES; i += 1024) nextkey[i] = 0ull;

    // p12 = dot(phi1, phi2) (128 elements)
    float pv = (t < 128) ? phi1[t] * phi2[t] : 0.0f;
    red[t] = pv; __syncthreads();
    for (int o = 512; o > 0; o >>= 1) { if (t < o) red[t] += red[t + o]; __syncthreads(); }
    float p12 = red[0]; __syncthreads();

    // max of h3 = acc3 + b3
    float b = b3[0];
    float lm = -INFINITY;
    for (int i = t; i < N_NODES; i += 1024) lm = fmaxf(lm, acc3[i] + b);
    red[t] = lm; __syncthreads();
    for (int o = 512; o > 0; o >>= 1) { if (t < o) red[t] = fmaxf(red[t], red[t + o]); __syncthreads(); }
    float M = red[0]; __syncthreads();

    // sum of exp
    float ls = 0.0f;
    for (int i = t; i < N_NODES; i += 1024) ls += expf(acc3[i] + b - M);
    red[t] = ls; __syncthreads();
    for (int o = 512; o > 0; o >>= 1) { if (t < o) red[t] += red[t + o]; __syncthreads(); }
    float S = red[0]; __syncthreads();

    // write softmax + argmax(xf) with first-index tie-break
    float bv = -INFINITY; int bi = 0x7fffffff;
    for (int i = t; i < N_NODES; i += 1024) {
        float v = expf(acc3[i] + b - M) / S;
        xo[i] = v;
        xf[i] = v;
        if (v > bv || (v == bv && i < bi)) { bv = v; bi = i; }
    }
    red[t] = bv; redi[t] = bi; __syncthreads();
    for (int o = 512; o > 0; o >>= 1) {
        if (t < o) {
            float v2 = red[t + o]; int i2 = redi[t + o];
            if (v2 > red[t] || (v2 == red[t] && i2 < redi[t])) { red[t] = v2; redi[t] = i2; }
        }
        __syncthreads();
    }
    if (t == 0) { scal[0] = p12; ((int*)scal)[1] = redi[0]; }
}

// per original edge: sc = tanh(((p12*xf[src])*xf[dst])*scale); argmax per src with
// first-index tie-break via packed (enc(sc) << 32 | ~j) atomicMax.
__global__ void k_chain_edges(const int* __restrict__ ei, const float* __restrict__ xf,
                              const float* __restrict__ scal,
                              unsigned long long* __restrict__ nextkey) {
    int j = blockIdx.x * blockDim.x + threadIdx.x;
    if (j >= E_EDGES) return;
    float p12 = scal[0];
    int s = ei[j], d = ei[E_EDGES + j];
    const float scale = 1.0f / sqrtf(128.0f);
    float tv = ((p12 * xf[s]) * xf[d]) * scale;   // exact reference op order
    float sc = tanhf(tv);
    unsigned long long key = ((unsigned long long)enc_f(sc) << 32)
                           | (unsigned long long)(~(unsigned)j);
    atomicMax(&nextkey[s], key);
}

// binary lifting: next^4096 via 12 doublings in LDS, then final = T[start]
__global__ __launch_bounds__(1024) void k_chain_resolve(
        const int* __restrict__ ei, const unsigned long long* __restrict__ nextkey,
        const float* __restrict__ scal, float* __restrict__ out_final) {
    __shared__ int A[N_NODES];
    __shared__ int B[N_NODES];
    int t = threadIdx.x;
    int d0 = ei[E_EDGES];          // dst0[0] — argmax over all -inf returns index 0
    for (int i = t; i < N_NODES; i += 1024) {
        unsigned long long key = nextkey[i];
        int nxt;
        if (key == 0ull) nxt = d0;
        else {
            unsigned j = ~(unsigned)(key & 0xFFFFFFFFull);
            nxt = ei[E_EDGES + j];
        }
        A[i] = nxt;
    }
    __syncthreads();
    for (int r = 0; r < 12; ++r) {    // 2^12 = 4096 applications
        for (int i = t; i < N_NODES; i += 1024) B[i] = A[A[i]];
        __syncthreads();
        for (int i = t; i < N_NODES; i += 1024) A[i] = B[i];
        __syncthreads();
    }
    if (t == 0) {
        int start = ((const int*)scal)[1];
        out_final[0] = (float)A[start];
    }
}

// ---------- launch ----------

extern "C" void kernel_launch(void* const* d_in, const int* in_sizes, int n_in,
                              void* d_out, int out_size, void* d_ws, size_t ws_size,
                              hipStream_t stream) {
    const float* x    = (const float*)d_in[0];
    const int*   ei   = (const int*)  d_in[1];
    const float* W1   = (const float*)d_in[2];
    const float* as1  = (const float*)d_in[3];
    const float* ad1  = (const float*)d_in[4];
    const float* b1   = (const float*)d_in[5];
    const float* W2   = (const float*)d_in[6];
    const float* as2  = (const float*)d_in[7];
    const float* ad2  = (const float*)d_in[8];
    const float* b2   = (const float*)d_in[9];
    const float* W3   = (const float*)d_in[10];
    const float* as3  = (const float*)d_in[11];
    const float* ad3  = (const float*)d_in[12];
    const float* b3   = (const float*)d_in[13];
    const float* phi1 = (const float*)d_in[14];
    const float* phi2 = (const float*)d_in[15];
    float* out = (float*)d_out;

    char* ws = (char*)d_ws;
    float*    z     = (float*)   (ws + 0);        // 3N floats
    float*    zs    = (float*)   (ws + 49152);    // N
    float*    zd    = (float*)   (ws + 65536);    // N
    unsigned* m_enc = (unsigned*)(ws + 81920);    // N
    float*    ssum  = (float*)   (ws + 98304);    // N
    float*    accA  = (float*)   (ws + 114688);   // 3N
    float*    accB  = (float*)   (ws + 163840);   // 3N
    float*    xf    = (float*)   (ws + 212992);   // N
    float*    scal  = (float*)   (ws + 229376);   // scalars
    unsigned long long* nextkey = (unsigned long long*)(ws + 229632); // N ull

    dim3 bn(256);
    dim3 gn((N_NODES + 255) / 256);
    dim3 ge((EL_TOTAL + 255) / 256);
    dim3 gc((E_EDGES + 255) / 256);

    // layer 1: x (N,1) -> accA (N,3)
    k_node_prep<1, 3, false><<<gn, bn, 0, stream>>>(x, nullptr, W1, as1, ad1, z, zs, zd, m_enc, ssum, accA);
    k_edge_max<<<ge, bn, 0, stream>>>(ei, zs, zd, m_enc);
    k_edge_sum<<<ge, bn, 0, stream>>>(ei, zs, zd, m_enc, ssum);
    k_edge_acc<3><<<ge, bn, 0, stream>>>(ei, zs, zd, m_enc, ssum, z, accA);

    // layer 2: relu(accA + b1) -> accB (N,3)
    k_node_prep<3, 3, true><<<gn, bn, 0, stream>>>(accA, b1, W2, as2, ad2, z, zs, zd, m_enc, ssum, accB);
    k_edge_max<<<ge, bn, 0, stream>>>(ei, zs, zd, m_enc);
    k_edge_sum<<<ge, bn, 0, stream>>>(ei, zs, zd, m_enc, ssum);
    k_edge_acc<3><<<ge, bn, 0, stream>>>(ei, zs, zd, m_enc, ssum, z, accB);

    // layer 3: relu(accB + b2) -> accA (N,1)
    k_node_prep<3, 1, true><<<gn, bn, 0, stream>>>(accB, b2, W3, as3, ad3, z, zs, zd, m_enc, ssum, accA);
    k_edge_max<<<ge, bn, 0, stream>>>(ei, zs, zd, m_enc);
    k_edge_sum<<<ge, bn, 0, stream>>>(ei, zs, zd, m_enc, ssum);
    k_edge_acc<1><<<ge, bn, 0, stream>>>(ei, zs, zd, m_enc, ssum, z, accA);

    // softmax (writes d_out[0..N)) + p12 + start + nextkey init
    k_softmax_prep<<<1, 1024, 0, stream>>>(accA, b3, phi1, phi2, out, xf, scal, nextkey);
    // chain next[] per source node
    k_chain_edges<<<gc, bn, 0, stream>>>(ei, xf, scal, nextkey);
    // 4096-step walk via binary lifting; writes d_out[N]
    k_chain_resolve<<<1, 1024, 0, stream>>>(ei, nextkey, scal, out + N_NODES);
}

// Round 2
// 224.606 us; speedup vs baseline: 1.2055x; 1.2055x over previous
//
#include <hip/hip_runtime.h>
#include <math.h>

#define N_NODES 4096
#define E_EDGES 131072
#define EL_TOTAL (E_EDGES + N_NODES)
#define NEG_SLOPE 0.2f

// ---------- helpers ----------

// order-preserving float->uint encoding (for packed 64-bit argmax keys)
__device__ __forceinline__ unsigned enc_f(float f) {
    unsigned u = __float_as_uint(f);
    return (u & 0x80000000u) ? ~u : (u | 0x80000000u);
}
__device__ __forceinline__ float lrelu(float x) {
    return x >= 0.0f ? x : NEG_SLOPE * x;
}
// edge j of the self-loop-augmented list: j<E -> edge_index, else self loop
__device__ __forceinline__ void edge_sd(const int* __restrict__ ei, int j, int& s, int& d) {
    if (j < E_EDGES) { s = ei[j]; d = ei[E_EDGES + j]; }
    else             { s = j - E_EDGES; d = s; }
}

// ---------- per-layer kernels ----------

// h = (NORM_PREV ? relu(accPrev/(ssum+eps) + bprev) : raw input)
// z = h @ W^T, zs = z@a_s, zd = z@a_d; re-inits ssum and accNext.
template<int F_IN, int F_OUT, bool NORM_PREV>
__global__ void k_node_prep(const float* __restrict__ hin, const float* __restrict__ bprev,
                            const float* __restrict__ W, const float* __restrict__ a_s,
                            const float* __restrict__ a_d,
                            float* __restrict__ z, float* __restrict__ zs, float* __restrict__ zd,
                            float* __restrict__ ssum, float* __restrict__ accNext) {
    int i = blockIdx.x * blockDim.x + threadIdx.x;
    if (i >= N_NODES) return;
    float inv = 1.0f;
    if constexpr (NORM_PREV) inv = 1.0f / (ssum[i] + 1e-16f);
    float h[F_IN];
#pragma unroll
    for (int m = 0; m < F_IN; ++m) {
        float v = hin[i * F_IN + m];
        if constexpr (NORM_PREV) { v = v * inv + bprev[m]; v = v > 0.0f ? v : 0.0f; }
        h[m] = v;
    }
    float zsv = 0.0f, zdv = 0.0f;
#pragma unroll
    for (int k = 0; k < F_OUT; ++k) {
        float zv = 0.0f;
#pragma unroll
        for (int m = 0; m < F_IN; ++m) zv += h[m] * W[k * F_IN + m];
        z[i * F_OUT + k] = zv;
        zsv += zv * a_s[k];
        zdv += zv * a_d[k];
        accNext[i * F_OUT + k] = 0.0f;
    }
    zs[i] = zsv;
    zd[i] = zdv;
    ssum[i] = 0.0f;
}

// fused softmax-weight + aggregate pass: w = exp(e) (no max subtraction — values
// are O(1..10), cannot overflow; max shift cancels in the w/s ratio).
template<int F_OUT>
__global__ void k_edge(const int* __restrict__ ei, const float* __restrict__ zs,
                       const float* __restrict__ zd, const float* __restrict__ z,
                       float* __restrict__ ssum, float* __restrict__ acc) {
    int j = blockIdx.x * blockDim.x + threadIdx.x;
    if (j >= EL_TOTAL) return;
    int s, d; edge_sd(ei, j, s, d);
    float w = expf(lrelu(zs[s] + zd[d]));
    atomicAdd(&ssum[d], w);
#pragma unroll
    for (int k = 0; k < F_OUT; ++k)
        atomicAdd(&acc[d * F_OUT + k], w * z[s * F_OUT + k]);
}

// ---------- softmax + chain prep (single block) ----------

__global__ __launch_bounds__(1024) void k_softmax_prep(
        const float* __restrict__ acc3, const float* __restrict__ ssum,
        const float* __restrict__ b3,
        const float* __restrict__ phi1, const float* __restrict__ phi2,
        float* __restrict__ xo, float* __restrict__ xf,
        float* __restrict__ scal, unsigned long long* __restrict__ nextkey) {
    __shared__ float red[1024];
    __shared__ int   redi[1024];
    int t = threadIdx.x;

    for (int i = t; i < N_NODES; i += 1024) nextkey[i] = 0ull;

    // p12 = dot(phi1, phi2) (128 elements)
    float pv = (t < 128) ? phi1[t] * phi2[t] : 0.0f;
    red[t] = pv; __syncthreads();
    for (int o = 512; o > 0; o >>= 1) { if (t < o) red[t] += red[t + o]; __syncthreads(); }
    float p12 = red[0]; __syncthreads();

    float b = b3[0];
    // h3 = acc3/(ssum+eps) + b ; max over nodes
    float lm = -INFINITY;
    for (int i = t; i < N_NODES; i += 1024)
        lm = fmaxf(lm, acc3[i] / (ssum[i] + 1e-16f) + b);
    red[t] = lm; __syncthreads();
    for (int o = 512; o > 0; o >>= 1) { if (t < o) red[t] = fmaxf(red[t], red[t + o]); __syncthreads(); }
    float M = red[0]; __syncthreads();

    // sum of exp
    float ls = 0.0f;
    for (int i = t; i < N_NODES; i += 1024)
        ls += expf(acc3[i] / (ssum[i] + 1e-16f) + b - M);
    red[t] = ls; __syncthreads();
    for (int o = 512; o > 0; o >>= 1) { if (t < o) red[t] += red[t + o]; __syncthreads(); }
    float S = red[0]; __syncthreads();

    // write softmax + argmax(xf) with first-index tie-break
    float bv = -INFINITY; int bi = 0x7fffffff;
    for (int i = t; i < N_NODES; i += 1024) {
        float v = expf(acc3[i] / (ssum[i] + 1e-16f) + b - M) / S;
        xo[i] = v;
        xf[i] = v;
        if (v > bv || (v == bv && i < bi)) { bv = v; bi = i; }
    }
    red[t] = bv; redi[t] = bi; __syncthreads();
    for (int o = 512; o > 0; o >>= 1) {
        if (t < o) {
            float v2 = red[t + o]; int i2 = redi[t + o];
            if (v2 > red[t] || (v2 == red[t] && i2 < redi[t])) { red[t] = v2; redi[t] = i2; }
        }
        __syncthreads();
    }
    if (t == 0) { scal[0] = p12; ((int*)scal)[1] = redi[0]; }
}

// per original edge: sc = tanh(((p12*xf[src])*xf[dst])*scale); argmax per src with
// first-index tie-break via packed (enc(sc) << 32 | ~j) atomicMax.
__global__ void k_chain_edges(const int* __restrict__ ei, const float* __restrict__ xf,
                              const float* __restrict__ scal,
                              unsigned long long* __restrict__ nextkey) {
    int j = blockIdx.x * blockDim.x + threadIdx.x;
    if (j >= E_EDGES) return;
    float p12 = scal[0];
    int s = ei[j], d = ei[E_EDGES + j];
    const float scale = 1.0f / sqrtf(128.0f);
    float tv = ((p12 * xf[s]) * xf[d]) * scale;   // exact reference op order
    float sc = tanhf(tv);
    unsigned long long key = ((unsigned long long)enc_f(sc) << 32)
                           | (unsigned long long)(~(unsigned)j);
    atomicMax(&nextkey[s], key);
}

// binary lifting: next^4096 via 12 doublings in LDS, then final = T[start]
__global__ __launch_bounds__(1024) void k_chain_resolve(
        const int* __restrict__ ei, const unsigned long long* __restrict__ nextkey,
        const float* __restrict__ scal, float* __restrict__ out_final) {
    __shared__ int A[N_NODES];
    __shared__ int B[N_NODES];
    int t = threadIdx.x;
    int d0 = ei[E_EDGES];          // dst0[0] — argmax over all -inf returns index 0
    for (int i = t; i < N_NODES; i += 1024) {
        unsigned long long key = nextkey[i];
        int nxt;
        if (key == 0ull) nxt = d0;
        else {
            unsigned j = ~(unsigned)(key & 0xFFFFFFFFull);
            nxt = ei[E_EDGES + j];
        }
        A[i] = nxt;
    }
    __syncthreads();
    for (int r = 0; r < 12; ++r) {    // 2^12 = 4096 applications
        for (int i = t; i < N_NODES; i += 1024) B[i] = A[A[i]];
        __syncthreads();
        for (int i = t; i < N_NODES; i += 1024) A[i] = B[i];
        __syncthreads();
    }
    if (t == 0) {
        int start = ((const int*)scal)[1];
        out_final[0] = (float)A[start];
    }
}

// ---------- launch ----------

extern "C" void kernel_launch(void* const* d_in, const int* in_sizes, int n_in,
                              void* d_out, int out_size, void* d_ws, size_t ws_size,
                              hipStream_t stream) {
    const float* x    = (const float*)d_in[0];
    const int*   ei   = (const int*)  d_in[1];
    const float* W1   = (const float*)d_in[2];
    const float* as1  = (const float*)d_in[3];
    const float* ad1  = (const float*)d_in[4];
    const float* W2   = (const float*)d_in[6];
    const float* as2  = (const float*)d_in[7];
    const float* ad2  = (const float*)d_in[8];
    const float* b1   = (const float*)d_in[5];
    const float* b2   = (const float*)d_in[9];
    const float* W3   = (const float*)d_in[10];
    const float* as3  = (const float*)d_in[11];
    const float* ad3  = (const float*)d_in[12];
    const float* b3   = (const float*)d_in[13];
    const float* phi1 = (const float*)d_in[14];
    const float* phi2 = (const float*)d_in[15];
    float* out = (float*)d_out;

    char* ws = (char*)d_ws;
    float*    z     = (float*)   (ws + 0);        // 3N floats
    float*    zs    = (float*)   (ws + 49152);    // N
    float*    zd    = (float*)   (ws + 65536);    // N
    float*    ssum  = (float*)   (ws + 81920);    // N
    float*    accA  = (float*)   (ws + 98304);    // 3N
    float*    accB  = (float*)   (ws + 147456);   // 3N
    float*    xf    = (float*)   (ws + 196608);   // N
    float*    scal  = (float*)   (ws + 212992);   // scalars
    unsigned long long* nextkey = (unsigned long long*)(ws + 213248); // N ull

    dim3 bn(256);
    dim3 gn((N_NODES + 255) / 256);
    dim3 ge((EL_TOTAL + 255) / 256);
    dim3 gc((E_EDGES + 255) / 256);

    // layer 1: x (N,1) -> accA (N,3), ssum
    k_node_prep<1, 3, false><<<gn, bn, 0, stream>>>(x, nullptr, W1, as1, ad1, z, zs, zd, ssum, accA);
    k_edge<3><<<ge, bn, 0, stream>>>(ei, zs, zd, z, ssum, accA);

    // layer 2: relu(accA/(ssum+eps) + b1) -> accB, ssum
    k_node_prep<3, 3, true><<<gn, bn, 0, stream>>>(accA, b1, W2, as2, ad2, z, zs, zd, ssum, accB);
    k_edge<3><<<ge, bn, 0, stream>>>(ei, zs, zd, z, ssum, accB);

    // layer 3: relu(accB/(ssum+eps) + b2) -> accA (N,1), ssum
    k_node_prep<3, 1, true><<<gn, bn, 0, stream>>>(accB, b2, W3, as3, ad3, z, zs, zd, ssum, accA);
    k_edge<1><<<ge, bn, 0, stream>>>(ei, zs, zd, z, ssum, accA);

    // softmax (writes d_out[0..N)) + p12 + start + nextkey init
    k_softmax_prep<<<1, 1024, 0, stream>>>(accA, ssum, b3, phi1, phi2, out, xf, scal, nextkey);
    // chain next[] per source node
    k_chain_edges<<<gc, bn, 0, stream>>>(ei, xf, scal, nextkey);
    // 4096-step walk via binary lifting; writes d_out[N]
    k_chain_resolve<<<1, 1024, 0, stream>>>(ei, nextkey, scal, out + N_NODES);
}